// Round 6
// baseline (58.296 us; speedup 1.0000x reference)
//
#include <hip/hip_runtime.h>
#include <math.h>

// Closed-form Thomas solve (telescoped Mobius recurrence): j = BC/(R+1).
// Latency-bound serial chain: 500 dependent iterations, 256 lanes (4 wave64).
//
// Post-switch the system is a clamped relaxation oscillator; chain surgery
// this round removes exp2 from the critical path EXACTLY:
//  - jump steps are detectable as T == 1.0f (prev fmax clamped) => r = 1
//    exactly => rho_jump is a pure function of i, computed off-chain with
//    identical rounding (fma(m,1,L)==m+L, rcp(1)==1).
//  - decay steps with T >= 2i have j <= 0.025 => linearized
//    rho_lin = fma(-40000*i, r, 8e6)   [8e6*ln2*C_EXPV = -40000 exactly]
//    rel err <= 3e-6 (ulp-class; R4 showed 5% fatal, ulp-class safe);
//    2e6 clamp provably non-binding (rho_lin >= 7.98e6).
//  - rare middle zone 1 < T < 2i: wave-voted fallback to exact exp2 path.
// Fast chain: rcp -> {fma s2 || fma rho_lin} -> sel -> fma -> fmax.

#define BATCH  256
#define NSTEPS 500
#define NOUT   251   // 1 leading zero + 250 recorded steps (every 2nd)

__global__ __launch_bounds__(64) void film_growth_kernel(
    const float* __restrict__ z, float* __restrict__ out)
{
#pragma clang fp contract(off)
    int b = blockIdx.x * 64 + threadIdx.x;
    if (b >= BATCH) return;

    const float z0 = z[3 * b + 0];
    const float K  = z[3 * b + 1];
    const float jm = z[3 * b + 2];

    const float VRDT = 0.05f;                    // VR*DT exact
    const float Cv   = powf(10.0f, -z0);
    const float CvDT = Cv * 0.5f;                // exact pow2 scale
    const float stepCvDT = VRDT * CvDT;          // i*stepCvDT = BC_i*Cv*DT
    const float mjmCvDT  = -jm * CvDT;

    // i==1 hoist: j1 = 0.05/2 = 0.025 exact -> beta = 0.05 exact
    const float Qmin = powf(81.0f / (128.0f * 0.05f), 1.0f / 3.0f)
                     * powf(K, 4.0f / 3.0f);

    const float C_EXPV = -0.14426950408889634f * VRDT; // -0.1*log2e*VR*DT
    const float L8E6   = 22.931568569324174f;          // log2(8e6)
    const float G1     = -40000.0f;                    // 8e6*ln2*C_EXPV exact

    float Q = 0.0f, h = 0.0f, T = 2.0f;          // T = R + 1

    float* o = out + (size_t)b * NOUT;
    o[0] = 0.0f;

    int i = 1;
    // ---- Phase A: until every lane in the wave has switched on ----
    for (; i <= NSTEPS; ++i) {
        const float fi = (float)i;

        const float r  = __builtin_amdgcn_rcpf(T);
        const float Qn = fmaf(0.025f * fi, r, Q);            // Q + j*DT
        const bool  w  = (Qn >= Qmin);                       // saturated sigmoid

        const float s2  = fmaf(fi * stepCvDT, r, mjmCvDT);   // (j-jm)*Cv*DT
        const float rho = fmaxf(
            __builtin_amdgcn_exp2f(fmaf(C_EXPV * fi, r, L8E6)), 2.0e6f);

        const float hn = w ? fmaxf(h + s2, 0.0f) : h;
        const float Tn = w ? fmaxf(fmaf(rho, s2, T), 1.0f) : T;

        Q = Qn; h = hn; T = Tn;
        if ((i & 1) == 0) o[i >> 1] = h;
        if (__all((int)w)) { ++i; break; }
    }

    // ---- Phase B: w==1 forever; exp2 moved off-chain via exact case split ----
    #pragma unroll 2
    for (; i <= NSTEPS; ++i) {
        const float fi  = (float)i;
        const float a_i = fi * stepCvDT;                     // off-chain
        const float m_i = C_EXPV * fi;                       // off-chain
        // jump-step rho (r==1 exact): pure function of i, off-chain
        const float rho_j = fmaxf(
            __builtin_amdgcn_exp2f(m_i + L8E6), 2.0e6f);
        const float Tthr  = 2.0f * fi;                       // j<=0.025 bound

        const bool jmp  = (T == 1.0f);
        const bool safe = jmp | (T >= Tthr);

        const float r  = __builtin_amdgcn_rcpf(T);           // chain
        const float s2 = fmaf(a_i, r, mjmCvDT);              // chain +1 fma

        float rho;
        if (__all((int)safe)) {
            // linear rho (rel err <= 3e-6), clamp non-binding; sel for jumps
            const float rho_lin = fmaf(G1 * fi, r, 8.0e6f);  // parallel w/ s2
            rho = jmp ? rho_j : rho_lin;
        } else {
            // exact path (any lane in 1 < T < Tthr)
            rho = fmaxf(
                __builtin_amdgcn_exp2f(fmaf(m_i, r, L8E6)), 2.0e6f);
        }

        T = fmaxf(fmaf(rho, s2, T), 1.0f);                   // chain tail
        h = fmaxf(h + s2, 0.0f);                             // parallel chain

        if ((i & 1) == 0) o[i >> 1] = h;
    }
}

extern "C" void kernel_launch(void* const* d_in, const int* in_sizes, int n_in,
                              void* d_out, int out_size, void* d_ws, size_t ws_size,
                              hipStream_t stream) {
    const float* z   = (const float*)d_in[0];
    float*       out = (float*)d_out;
    film_growth_kernel<<<dim3((BATCH + 63) / 64), dim3(64), 0, stream>>>(z, out);
}

// Round 7
// 47.835 us; speedup vs baseline: 1.2187x; 1.2187x over previous
//
#include <hip/hip_runtime.h>
#include <math.h>

// Closed-form Thomas solve (telescoped Mobius recurrence): j = BC/(R+1).
// Latency-bound serial chain: 500 dependent iterations, 256 lanes (4 wave64).
// Latency model (fits R1/R2/R5/R6): trans dep-latency ~60cy, ALU ~5cy.
//
// Numeric partition (bit-validated by R6's passing run, absmax identical):
//   - safe zone  j <= 0.025 (T >= 2i): rho_lin = fma(-40000*i, r, 8e6),
//     rel err <= 3e-6, 2e6 clamp provably non-binding.
//   - bad zone   T < 2i (jump steps T==1, soft jumps, ramp bottoms, and all
//     clamp-binding steps j>=13.86): exact reference rho via exp2.
// Control restructure vs R6 (which lost 130cy/iter to exec-mask if/else +
// per-iter extra exp2): 'bad' depends ONLY on T, known at iteration start;
// the wave-uniform __any vote + s_cbranch resolves under rcp's 60cy latency.
// Common-iter chain: rcp(60) -> {fma s2 || fma rho_lin} -> fma -> fmax ~75cy.

#define BATCH  256
#define NSTEPS 500
#define NOUT   251   // 1 leading zero + 250 recorded steps (every 2nd)

__global__ __launch_bounds__(64) void film_growth_kernel(
    const float* __restrict__ z, float* __restrict__ out)
{
#pragma clang fp contract(off)
    int b = blockIdx.x * 64 + threadIdx.x;
    if (b >= BATCH) return;

    const float z0 = z[3 * b + 0];
    const float K  = z[3 * b + 1];
    const float jm = z[3 * b + 2];

    const float Cv   = powf(10.0f, -z0);
    const float CvDT = Cv * 0.5f;                // exact pow2 scale
    const float stepCvDT = 0.05f * CvDT;         // i*stepCvDT = BC_i*Cv*DT
    const float mjmCvDT  = -jm * CvDT;

    // i==1 hoist: j1 = 0.05/2 = 0.025 exact -> beta = 0.05 exact
    const float Qmin = powf(81.0f / (128.0f * 0.05f), 1.0f / 3.0f)
                     * powf(K, 4.0f / 3.0f);

    const float C_EXPV = -0.14426950408889634f * 0.05f; // -0.1*log2e*VR*DT
    const float L8E6   = 22.931568569324174f;           // log2(8e6)
    const float G1     = -40000.0f;                     // 8e6*ln2*C_EXPV exact

    float Q = 0.0f, h = 0.0f, T = 2.0f;          // T = R + 1

    float* o = out + (size_t)b * NOUT;
    o[0] = 0.0f;

    int i = 1;
    // ---- Phase A: exact rho every step, until all lanes switch on ----
    for (; i <= NSTEPS; ++i) {
        const float fi = (float)i;

        const float r  = __builtin_amdgcn_rcpf(T);
        const float Qn = fmaf(0.025f * fi, r, Q);            // Q + j*DT
        const bool  w  = (Qn >= Qmin);                       // saturated sigmoid

        const float s2  = fmaf(fi * stepCvDT, r, mjmCvDT);   // (j-jm)*Cv*DT
        const float rho = fmaxf(
            __builtin_amdgcn_exp2f(fmaf(C_EXPV * fi, r, L8E6)), 2.0e6f);

        const float hn = w ? fmaxf(h + s2, 0.0f) : h;
        const float Tn = w ? fmaxf(fmaf(rho, s2, T), 1.0f) : T;

        Q = Qn; h = hn; T = Tn;
        if ((i & 1) == 0) o[i >> 1] = h;
        if (__all((int)w)) { ++i; break; }
    }

    // ---- Phase B: w==1 forever; single-trans common path ----
    #pragma unroll 2
    for (; i <= NSTEPS; ++i) {
        const float fi = (float)i;

        // Vote on T only (available at iter start) -> uniform s_cbranch
        // resolves while rcp is in flight.
        const bool bad = (T < 2.0f * fi);        // jump/soft-jump/bottom/clamp

        const float r  = __builtin_amdgcn_rcpf(T);           // chain: 60cy
        const float s2 = fmaf(fi * stepCvDT, r, mjmCvDT);    // chain +5

        float rho = fmaf(G1 * fi, r, 8.0e6f);    // parallel with s2 (safe zone)
        if (__any((int)bad)) {
            // exact reference rho (valid for every lane; jump lanes r==1
            // reproduce rho_j bit-exactly incl. the 2e6 clamp)
            rho = fmaxf(
                __builtin_amdgcn_exp2f(fmaf(C_EXPV * fi, r, L8E6)), 2.0e6f);
        }

        T = fmaxf(fmaf(rho, s2, T), 1.0f);                   // chain +10
        h = fmaxf(h + s2, 0.0f);                             // parallel chain

        if ((i & 1) == 0) o[i >> 1] = h;
    }
}

extern "C" void kernel_launch(void* const* d_in, const int* in_sizes, int n_in,
                              void* d_out, int out_size, void* d_ws, size_t ws_size,
                              hipStream_t stream) {
    const float* z   = (const float*)d_in[0];
    float*       out = (float*)d_out;
    film_growth_kernel<<<dim3((BATCH + 63) / 64), dim3(64), 0, stream>>>(z, out);
}

// Round 9
// 47.673 us; speedup vs baseline: 1.2228x; 1.0034x over previous
//
#include <hip/hip_runtime.h>
#include <math.h>

// Closed-form Thomas solve (telescoped Mobius recurrence): j = BC/(R+1).
// Latency-bound serial chain; trans dep-latency ~65cy (fits R1/R2/R5/R6).
// Lessons: no votes/branches in inner loop (R6/R7); %-level perturbations
// fatal, ulp-class safe (R4 vs 5 bit-stable rounds); R8's failure was a
// WRONG NEWTON SEED (5.647-7.529m crosses zero at m=0.75), not the method.
//
// Phase B replaces both transcendentals with short ALU chains, ~ulp accuracy:
//  - 1/T: bit-split T=m*2^e (T>=1: normal, positive), seed 48/17-32/17*m
//    (max err 1/17), 3 Newton steps (~1e-10 rel -> 0.5-1ulp), scale by
//    bit-built 2^-e.                                            (~40cy)
//  - rho = fmax(8e6*exp2(C_EXP*j), 2e6) = exp2(fmax(arg, log2(2e6))),
//    arg = fma(C_EXPV*fi, r, L8E6) — IDENTICAL to reference rounding;
//    post-clamp x in [20.93,22.93] => n in {21,22,23}; deg-6 Taylor on
//    f in [-0.5,0.5], rel err <= 2e-7; scale by bit-built 2^n.  (~48cy)

#define BATCH  256
#define NSTEPS 500
#define NOUT   251   // 1 leading zero + 250 recorded steps (every 2nd)

__global__ __launch_bounds__(64) void film_growth_kernel(
    const float* __restrict__ z, float* __restrict__ out)
{
#pragma clang fp contract(off)
    int b = blockIdx.x * 64 + threadIdx.x;
    if (b >= BATCH) return;

    const float z0 = z[3 * b + 0];
    const float K  = z[3 * b + 1];
    const float jm = z[3 * b + 2];

    const float Cv   = powf(10.0f, -z0);
    const float CvDT = Cv * 0.5f;                 // exact pow2 scale
    const float stepCvDT = 0.05f * CvDT;          // i*stepCvDT = BC_i*Cv*DT
    const float mjmCvDT  = -jm * CvDT;

    // i==1 hoist: j1 = 0.05/2 = 0.025 exact -> beta = 0.05 exact
    const float Qmin = powf(81.0f / (128.0f * 0.05f), 1.0f / 3.0f)
                     * powf(K, 4.0f / 3.0f);

    const float C_EXPV = -0.14426950408889634f * 0.05f; // -0.1*log2e*VR*DT
    const float L8E6   = 22.931568569324174f;           // log2(8e6)
    const float L2E6   = 20.931568569324174f;           // log2(2e6)

    float Q = 0.0f, h = 0.0f, T = 2.0f;           // T = R + 1

    float* o = out + (size_t)b * NOUT;
    o[0] = 0.0f;

    int i = 1;
    // ---- Phase A: exact hardware trans until all lanes switch (~20 iters) ----
    for (; i <= NSTEPS; ++i) {
        const float fi = (float)i;

        const float r  = __builtin_amdgcn_rcpf(T);
        const float Qn = fmaf(0.025f * fi, r, Q);            // Q + j*DT
        const bool  w  = (Qn >= Qmin);                       // saturated sigmoid

        const float s2  = fmaf(fi * stepCvDT, r, mjmCvDT);   // (j-jm)*Cv*DT
        const float rho = fmaxf(
            __builtin_amdgcn_exp2f(fmaf(C_EXPV * fi, r, L8E6)), 2.0e6f);

        const float hn = w ? fmaxf(h + s2, 0.0f) : h;
        const float Tn = w ? fmaxf(fmaf(rho, s2, T), 1.0f) : T;

        Q = Qn; h = hn; T = Tn;
        if ((i & 1) == 0) o[i >> 1] = h;
        if (__all((int)w)) { ++i; break; }
    }

    // ---- Phase B: straightline ALU-only chain, no votes/branches ----
    #pragma unroll 2
    for (; i <= NSTEPS; ++i) {
        const float fi  = (float)i;
        const float a_i = fi * stepCvDT;                     // off-chain
        const float m_i = C_EXPV * fi;                       // off-chain

        // software reciprocal r = 1/T  (T >= 1: normal, positive)
        const unsigned tb = __float_as_uint(T);
        const int   ee  = (int)(tb >> 23) - 126;             // T = m*2^ee
        const float mm  = __uint_as_float((tb & 0x007FFFFFu) | 0x3F000000u); // [0.5,1)
        const float scl = __uint_as_float((unsigned)(127 - ee) << 23);       // 2^-ee
        float r = fmaf(-1.8823529f, mm, 2.8235294f);         // seed 48/17-32/17*m
        r = fmaf(fmaf(-mm, r, 1.0f), r, r);                  // NR1
        r = fmaf(fmaf(-mm, r, 1.0f), r, r);                  // NR2
        r = fmaf(fmaf(-mm, r, 1.0f), r, r);                  // NR3 (~0.5-1 ulp)
        r = r * scl;                                         // 1/T

        const float s2 = fmaf(a_i, r, mjmCvDT);              // (j-jm)*Cv*DT

        // software exp2 with folded 2e6 clamp; arg rounding == reference
        const float x  = fmaxf(fmaf(m_i, r, L8E6), L2E6);    // [20.93,22.93]
        const float nf = rintf(x);                           // {21,22,23}
        const float f  = x - nf;                             // [-0.5,0.5]
        const float s2n = __uint_as_float((unsigned)(127 + (int)nf) << 23); // 2^n
        float p = 1.5403530e-4f;                             // ln2^6/720
        p = fmaf(p, f, 1.3333558e-3f);                       // ln2^5/120
        p = fmaf(p, f, 9.6181291e-3f);                       // ln2^4/24
        p = fmaf(p, f, 5.5504109e-2f);                       // ln2^3/6
        p = fmaf(p, f, 2.4022651e-1f);                       // ln2^2/2
        p = fmaf(p, f, 6.9314718e-1f);                       // ln2
        p = fmaf(p, f, 1.0f);
        const float rho = p * s2n;                           // fmax(exp2,2e6)

        T = fmaxf(fmaf(rho, s2, T), 1.0f);                   // chain tail
        h = fmaxf(h + s2, 0.0f);                             // parallel chain

        if ((i & 1) == 0) o[i >> 1] = h;
    }
}

extern "C" void kernel_launch(void* const* d_in, const int* in_sizes, int n_in,
                              void* d_out, int out_size, void* d_ws, size_t ws_size,
                              hipStream_t stream) {
    const float* z   = (const float*)d_in[0];
    float*       out = (float*)d_out;
    film_growth_kernel<<<dim3((BATCH + 63) / 64), dim3(64), 0, stream>>>(z, out);
}

// Round 10
// 31.651 us; speedup vs baseline: 1.8418x; 1.5062x over previous
//
#include <hip/hip_runtime.h>
#include <math.h>

// Closed-form Thomas solve (telescoped Mobius recurrence): j = BC/(R+1).
// Latency-bound serial chain: 500 dependent iterations, 256 lanes (4 wave64).
//
// FINAL latency model (fit across R1/R2/R5/R7/R9): dependent-VALU ~12cy,
// hardware trans (v_rcp/v_exp) dependent latency ~55cy. Exact per-iter chain
// rcp -> arg-fma -> clamp -> exp2 -> T-fma -> T-clamp ~ 158cy; measured 152.
// Structural floor: the two transcendentals are irreducible (rho must be
// exact whenever T < 2i — middle-zone events occur dozens of times in this
// dataset per the oscillator dynamics — and software trans chains are
// slower than hardware at 12cy/fma). All shorter structures tried and
// rejected: lagged rho (R4, fatal), per-iter branch (R6, +130cy), wave vote
// (R7, +80cy), software trans (R9, +77cy), quadratic fast-path (unsafe:
// middle-zone %-error, R4-class).
//
// Ulp-safe chain cuts vs the naive exact loop:
//  - state T = R+1: T' = max(fma(rho,s2,T),1)   (kills the pre-rcp add)
//  - s2 in one fma: s2 = fma(i*VRDT*CvDT, r, -jm*CvDT) = (j-jm)*Cv*DT
//  - v_rcp (no Newton), v_exp2 direct — ~1ulp, below the bit-stable
//    closed-form-vs-scan offset (absmax 4.664062, 6 rounds bit-identical).

#define BATCH  256
#define NSTEPS 500
#define NOUT   251   // 1 leading zero + 250 recorded steps (every 2nd)

__global__ __launch_bounds__(64) void film_growth_kernel(
    const float* __restrict__ z, float* __restrict__ out)
{
#pragma clang fp contract(off)
    int b = blockIdx.x * 64 + threadIdx.x;
    if (b >= BATCH) return;

    const float z0 = z[3 * b + 0];
    const float K  = z[3 * b + 1];
    const float jm = z[3 * b + 2];

    const float VRDT = 0.05f;                    // VR*DT exact
    const float Cv   = powf(10.0f, -z0);
    const float CvDT = Cv * 0.5f;                // exact pow2 scale
    const float stepCvDT = VRDT * CvDT;          // i*stepCvDT = BC_i*Cv*DT
    const float mjmCvDT  = -jm * CvDT;

    // i==1 hoist: j1 = 0.05/2 = 0.025 exact -> beta = 0.05 exact
    const float Qmin = powf(81.0f / (128.0f * 0.05f), 1.0f / 3.0f)
                     * powf(K, 4.0f / 3.0f);

    const float C_EXPV = -0.14426950408889634f * 0.05f; // -0.1*log2e*VR*DT
    const float L8E6   = 22.931568569324174f;           // log2(8e6)

    float Q = 0.0f, h = 0.0f, T = 2.0f;          // T = R + 1

    float* o = out + (size_t)b * NOUT;
    o[0] = 0.0f;

    int i = 1;
    // ---- Phase A: until every lane in the wave has switched on ----
    for (; i <= NSTEPS; ++i) {
        const float fi = (float)i;

        const float r  = __builtin_amdgcn_rcpf(T);
        const float Qn = fmaf(0.025f * fi, r, Q);            // Q + j*DT
        const bool  w  = (Qn >= Qmin);                       // saturated sigmoid

        const float s2  = fmaf(fi * stepCvDT, r, mjmCvDT);   // (j-jm)*Cv*DT
        const float rho = fmaxf(
            __builtin_amdgcn_exp2f(fmaf(C_EXPV * fi, r, L8E6)), 2.0e6f);

        const float hn = w ? fmaxf(h + s2, 0.0f) : h;
        const float Tn = w ? fmaxf(fmaf(rho, s2, T), 1.0f) : T;

        Q = Qn; h = hn; T = Tn;
        if ((i & 1) == 0) o[i >> 1] = h;
        if (__all((int)w)) { ++i; break; }
    }

    // ---- Phase B: w==1 forever; Q/compare/selects dropped; same-step rho ----
    #pragma unroll 2
    for (; i <= NSTEPS; ++i) {
        const float fi = (float)i;

        const float r   = __builtin_amdgcn_rcpf(T);          // T -> r
        const float s2  = fmaf(fi * stepCvDT, r, mjmCvDT);   // r -> s2
        const float rho = fmaxf(
            __builtin_amdgcn_exp2f(fmaf(C_EXPV * fi, r, L8E6)), 2.0e6f);

        T = fmaxf(fmaf(rho, s2, T), 1.0f);                   // rho,s2 -> T'
        h = fmaxf(h + s2, 0.0f);                             // parallel chain

        if ((i & 1) == 0) o[i >> 1] = h;
    }
}

extern "C" void kernel_launch(void* const* d_in, const int* in_sizes, int n_in,
                              void* d_out, int out_size, void* d_ws, size_t ws_size,
                              hipStream_t stream) {
    const float* z   = (const float*)d_in[0];
    float*       out = (float*)d_out;
    film_growth_kernel<<<dim3((BATCH + 63) / 64), dim3(64), 0, stream>>>(z, out);
}